// Round 15
// baseline (260.514 us; speedup 1.0000x reference)
//
#include <hip/hip_runtime.h>

#define NN 4096
#define HID 512
#define NH 8
#define HD 64

typedef __attribute__((ext_vector_type(8))) short short8;
typedef __attribute__((ext_vector_type(4))) float f32x4;

__device__ __forceinline__ ushort f2bf(float f) {
    unsigned u = __float_as_uint(f);
    return (ushort)((u + 0x7FFFu + ((u >> 16) & 1u)) >> 16);   // RNE
}
__device__ __forceinline__ float bf2f(ushort h) {
    return __uint_as_float((unsigned)h << 16);
}

__device__ __forceinline__ void gld16(const void* g, void* l) {
    __builtin_amdgcn_global_load_lds(
        (const __attribute__((address_space(1))) void*)g,
        (__attribute__((address_space(3))) void*)l, 16, 0, 0);
}

// ---------------- cvt_x: x (f32) -> xh + xl (bf16 split) ----------------
__global__ __launch_bounds__(256) void cvt_x_kernel(
    const float* __restrict__ x, ushort* __restrict__ xh, ushort* __restrict__ xl)
{
    int i = (blockIdx.x * 256 + threadIdx.x) * 8;
    float4 v0 = *(const float4*)(x + i);
    float4 v1 = *(const float4*)(x + i + 4);
    float v[8] = {v0.x, v0.y, v0.z, v0.w, v1.x, v1.y, v1.z, v1.w};
    ushort h[8], l[8];
#pragma unroll
    for (int j = 0; j < 8; ++j) {
        h[j] = f2bf(v[j]);
        l[j] = f2bf(v[j] - bf2f(h[j]));
    }
    ushort4 u;
    u.x = h[0]; u.y = h[1]; u.z = h[2]; u.w = h[3]; *(ushort4*)(xh + i) = u;
    u.x = h[4]; u.y = h[5]; u.z = h[6]; u.w = h[7]; *(ushort4*)(xh + i + 4) = u;
    u.x = l[0]; u.y = l[1]; u.z = l[2]; u.w = l[3]; *(ushort4*)(xl + i) = u;
    u.x = l[4]; u.y = l[5]; u.z = l[6]; u.w = l[7]; *(ushort4*)(xl + i + 4) = u;
}

// ---------------- cvt_w: W (f32 [512][512]) -> packed hi/lo bf16 ----------------
__global__ __launch_bounds__(256) void cvt_w_kernel(
    const float* __restrict__ Wq, const float* __restrict__ Wk,
    const float* __restrict__ Wv,
    ushort* __restrict__ Wph, ushort* __restrict__ Wpl)
{
    const int mat = blockIdx.z;
    const float* W = (mat == 0) ? Wq : ((mat == 1) ? Wk : Wv);
    const int col = blockIdx.x * 256 + threadIdx.x;
    const int kcb = blockIdx.y;
    ushort* dh = Wph + (size_t)mat * 262144 + kcb * 16384 + col * 32;
    ushort* dl = Wpl + (size_t)mat * 262144 + kcb * 16384 + col * 32;
#pragma unroll
    for (int k4 = 0; k4 < 8; ++k4) {
        ushort4 uh, ul;
#pragma unroll
        for (int j = 0; j < 4; ++j) {
            float v = W[(size_t)(kcb * 32 + k4 * 4 + j) * HID + col];
            ushort h = f2bf(v);
            (&uh.x)[j] = h;
            (&ul.x)[j] = f2bf(v - bf2f(h));
        }
        *(ushort4*)(dh + k4 * 4) = uh;
        *(ushort4*)(dl + k4 * 4) = ul;
    }
}

// ---------------- qkv via MFMA, 3-split (xh@Wh + xh@Wl + xl@Wh) ----------------
__global__ __launch_bounds__(256) void qkv_mfma_kernel(
    const ushort* __restrict__ xh, const ushort* __restrict__ xl,
    const ushort* __restrict__ Wph, const ushort* __restrict__ Wpl,
    const float* __restrict__ bq, const float* __restrict__ bk,
    const float* __restrict__ bv,
    ushort* __restrict__ Qb, char* __restrict__ Kbs, char* __restrict__ Vts)
{
    const int mat = blockIdx.z;
    const int row0 = blockIdx.y * 128;
    const int col0 = blockIdx.x * 64;
    const int tid = threadIdx.x;
    const int w = tid >> 6, lane = tid & 63, g = lane >> 4, li = lane & 15;
    const ushort* Bh = Wph + (size_t)mat * 262144;
    const ushort* Bl = Wpl + (size_t)mat * 262144;
    const float* bias = (mat == 0) ? bq : ((mat == 1) ? bk : bv);

    __shared__ __align__(16) char smem[18432];

    f32x4 acc[2][4];
#pragma unroll
    for (int sb = 0; sb < 2; ++sb)
#pragma unroll
        for (int cf = 0; cf < 4; ++cf) acc[sb][cf] = (f32x4){0.f, 0.f, 0.f, 0.f};

    const ushort* xr0h = xh + (size_t)(row0 + w * 32 + li) * HID;
    const ushort* xr1h = xr0h + 16 * HID;
    const ushort* xr0l = xl + (size_t)(row0 + w * 32 + li) * HID;
    const ushort* xr1l = xr0l + 16 * HID;

#pragma unroll 2
    for (int kcb = 0; kcb < 16; ++kcb) {
        const int ko = kcb * 32 + g * 8;
        short8 a0h = *(const short8*)(xr0h + ko);
        short8 a1h = *(const short8*)(xr1h + ko);
        short8 a0l = *(const short8*)(xr0l + ko);
        short8 a1l = *(const short8*)(xr1l + ko);
        const ushort* bbh = Bh + kcb * 16384 + (col0 + li) * 32 + g * 8;
        const ushort* bbl = Bl + kcb * 16384 + (col0 + li) * 32 + g * 8;
#pragma unroll
        for (int cf = 0; cf < 4; ++cf) {
            short8 bhf = *(const short8*)(bbh + cf * 512);
            short8 blf = *(const short8*)(bbl + cf * 512);
            acc[0][cf] = __builtin_amdgcn_mfma_f32_16x16x32_bf16(a0l, bhf, acc[0][cf], 0, 0, 0);
            acc[0][cf] = __builtin_amdgcn_mfma_f32_16x16x32_bf16(a0h, blf, acc[0][cf], 0, 0, 0);
            acc[0][cf] = __builtin_amdgcn_mfma_f32_16x16x32_bf16(a0h, bhf, acc[0][cf], 0, 0, 0);
            acc[1][cf] = __builtin_amdgcn_mfma_f32_16x16x32_bf16(a1l, bhf, acc[1][cf], 0, 0, 0);
            acc[1][cf] = __builtin_amdgcn_mfma_f32_16x16x32_bf16(a1h, blf, acc[1][cf], 0, 0, 0);
            acc[1][cf] = __builtin_amdgcn_mfma_f32_16x16x32_bf16(a1h, bhf, acc[1][cf], 0, 0, 0);
        }
    }

    float bv_f[4];
#pragma unroll
    for (int cf = 0; cf < 4; ++cf) bv_f[cf] = bias[col0 + cf * 16 + li];

    const int head = col0 >> 6;
    if (mat < 2) {
        ushort* st = (ushort*)smem;          // [128][72]
#pragma unroll
        for (int sb = 0; sb < 2; ++sb)
#pragma unroll
            for (int cf = 0; cf < 4; ++cf)
#pragma unroll
                for (int r = 0; r < 4; ++r)
                    st[(w * 32 + sb * 16 + g * 4 + r) * 72 + cf * 16 + li] =
                        f2bf(acc[sb][cf][r] + bv_f[cf]);
        __syncthreads();
        int row = tid >> 1, hf = tid & 1;
        const ushort* src = st + row * 72 + hf * 32;
        if (mat == 0) {
            ushort* dst = Qb + ((size_t)head * NN + row0 + row) * HD + hf * 32;
#pragma unroll
            for (int c = 0; c < 4; ++c)
                *(uint4*)(dst + c * 8) = *(const uint4*)(src + c * 8);
        } else {
            char* dst = Kbs + ((size_t)head * NN + row0 + row) * 128;
#pragma unroll
            for (int j8 = 0; j8 < 4; ++j8) {
                int j = hf * 4 + j8;
                *(uint4*)(dst + ((j * 16) ^ ((row & 7) << 4))) =
                    *(const uint4*)(st + row * 72 + j * 8);
            }
        }
    } else {
        ushort* vst = (ushort*)smem;         // [64][136]
#pragma unroll
        for (int sb = 0; sb < 2; ++sb)
#pragma unroll
            for (int cf = 0; cf < 4; ++cf) {
                ushort4 pk;
                pk.x = f2bf(acc[sb][cf][0] + bv_f[cf]);
                pk.y = f2bf(acc[sb][cf][1] + bv_f[cf]);
                pk.z = f2bf(acc[sb][cf][2] + bv_f[cf]);
                pk.w = f2bf(acc[sb][cf][3] + bv_f[cf]);
                *(ushort4*)(vst + (cf * 16 + li) * 136 + w * 32 + sb * 16 + g * 4) = pk;
            }
        __syncthreads();
        int cl = tid >> 2, q = tid & 3;
        int dsw = (cl & 7) << 4;
        char* dstrow = Vts + (size_t)(col0 + cl) * (NN * 2);
        int colb0 = (row0 + q * 32) * 2;
#pragma unroll
        for (int k8 = 0; k8 < 4; ++k8)
            *(uint4*)(dstrow + ((colb0 + k8 * 16) ^ dsw)) =
                *(const uint4*)(vst + cl * 136 + q * 32 + k8 * 8);
    }
}

// ---------------- Kernel B: fused attention ----------------
// grid 1024, block 256 (4 waves). 32 q-rows/block; wave w: rgrp=w>>1 (16 rows),
// khalf=w&1 (2048 k). 32-col k-tiles, 64 iters/pass. LDS 40KB -> 4 blocks/CU.
// Pass A: QUAD-buffered K (3-tile lookahead, vmcnt(4)). Pass B: R14 proven.
__global__ __launch_bounds__(256, 4) void attn_kernel(
    const ushort* __restrict__ Qb, const char* __restrict__ Kbs,
    const char* __restrict__ Vts,
    float* __restrict__ wout, float* __restrict__ att)
{
    const int bid = blockIdx.x;
    const int h = bid & 7;
    const int row0 = (bid >> 3) * 32;
    const int tid = threadIdx.x;
    const int w = tid >> 6, lane = tid & 63;
    const int g = lane >> 4, li = lane & 15;
    const int rgrp = w >> 1, khalf = w & 1;
    const int qr = row0 + rgrp * 16;

    const ushort* Qh = Qb + (size_t)h * NN * HD;
    const char* Kh = Kbs + (size_t)h * NN * 128;
    const char* Vh = Vts + (size_t)h * HD * NN * 2;
    float* WH = wout + ((size_t)h << 24);

    // LDS 40960B: kbuf0|kbuf1 8KB, vbuf0|vbuf1 8KB, pbuf 8KB (4x2KB).
    __shared__ __align__(16) char smem[40960];
    char* kbuf0 = smem;
    char* kbuf1 = smem + 8192;
    char* vbuf0 = smem + 16384;
    char* vbuf1 = smem + 24576;
    char* pbuf  = smem + 32768;
    float* zpart = (float*)(smem + 32768);      // [4][16] overlay
    float* attstage = (float*)(smem + 32768);   // [32][64] overlay

    const short8 qa0 = *(const short8*)(Qh + (size_t)(qr + li) * HD + g * 8);
    const short8 qa1 = *(const short8*)(Qh + (size_t)(qr + li) * HD + 32 + g * 8);
    const int sw = (li & 7) << 4;

    // staging geometry (per thread, 2 gld16 per 8KB buffer)
    const int r0 = w * 8 + (lane >> 3);
    const int inb = (lane & 7) * 16;
    const int L0 = w * 1024 + lane * 16;
    // V slot map (verified R14)
    const int d0 = r0;
    const int hs = (lane & 7) ^ (d0 & 7);
    const int vh = hs >> 2, vs = hs & 3;
    const int vdsw = d0 & 7;
    const int vro = (((khalf << 2) | g) ^ (li & 7)) << 4;

    // ---- Pass A: Z (QUAD-buffered K: kbuf0, kbuf1, vbuf0, vbuf1) ----
    float zsum = 0.f;
    {
        char* c0 = kbuf0; char* c1 = kbuf1; char* c2 = vbuf0; char* c3 = vbuf1;
        gld16(Kh + (size_t)(r0) * 128 + inb, c0 + L0);
        gld16(Kh + (size_t)(2048 + r0) * 128 + inb, c0 + L0 + 4096);
        gld16(Kh + (size_t)(r0 + 32) * 128 + inb, c1 + L0);
        gld16(Kh + (size_t)(2048 + r0 + 32) * 128 + inb, c1 + L0 + 4096);
        gld16(Kh + (size_t)(r0 + 64) * 128 + inb, c2 + L0);
        gld16(Kh + (size_t)(2048 + r0 + 64) * 128 + inb, c2 + L0 + 4096);
        asm volatile("" ::: "memory");
        for (int t = 0; t < 64; ++t) {
            if (t < 62)      { asm volatile("s_waitcnt vmcnt(4)" ::: "memory"); }
            else if (t == 62){ asm volatile("s_waitcnt vmcnt(2)" ::: "memory"); }
            else             { asm volatile("s_waitcnt vmcnt(0)" ::: "memory"); }
            __builtin_amdgcn_s_barrier();
            if (t + 3 < 64) {
                gld16(Kh + (size_t)(r0 + (t + 3) * 32) * 128 + inb, c3 + L0);
                gld16(Kh + (size_t)(2048 + r0 + (t + 3) * 32) * 128 + inb, c3 + L0 + 4096);
            }
            asm volatile("" ::: "memory");
#pragma unroll
            for (int jt = 0; jt < 2; ++jt) {
                const char* rp = c0 + (khalf * 32 + jt * 16 + li) * 128;
                short8 kb0 = *(const short8*)(rp + ((g * 16) ^ sw));
                short8 kb1 = *(const short8*)(rp + ((64 + g * 16) ^ sw));
                f32x4 acc = {0.f, 0.f, 0.f, 0.f};
                acc = __builtin_amdgcn_mfma_f32_16x16x32_bf16(kb0, qa0, acc, 0, 0, 0);
                acc = __builtin_amdgcn_mfma_f32_16x16x32_bf16(kb1, qa1, acc, 0, 0, 0);
#pragma unroll
                for (int r = 0; r < 4; ++r) zsum += __expf(acc[r] * 0.125f);
            }
            char* tmp = c0; c0 = c1; c1 = c2; c2 = c3; c3 = tmp;
        }
    }
    zsum += __shfl_xor(zsum, 16);
    zsum += __shfl_xor(zsum, 32);
    if (lane < 16) zpart[w * 16 + li] = zsum;
    __syncthreads();
    const float iz = 1.0f / (zpart[(rgrp * 2) * 16 + li] + zpart[(rgrp * 2 + 1) * 16 + li]);
    __syncthreads();   // zpart consumed before pbuf overlay is written

    // ---- Pass B: normalized weights + P@V (R14 proven) ----
    f32x4 pv[4];
#pragma unroll
    for (int dt = 0; dt < 4; ++dt) pv[dt] = (f32x4){0.f, 0.f, 0.f, 0.f};
    char* myp = pbuf + w * 2048;

    {
        char* kc = kbuf0; char* kn = kbuf1;
        char* vc = vbuf0; char* vn = vbuf1;
        gld16(Kh + (size_t)(r0) * 128 + inb, kc + L0);
        gld16(Kh + (size_t)(2048 + r0) * 128 + inb, kc + L0 + 4096);
        {
            size_t tail0 = (size_t)vh * 4096 + ((vs ^ vdsw) << 4);
            gld16(Vh + (size_t)d0 * 8192 + tail0, vc + L0);
            gld16(Vh + (size_t)(d0 + 32) * 8192 + tail0, vc + L0 + 4096);
        }
        asm volatile("" ::: "memory");
        for (int t = 0; t < 64; ++t) {
            if (t == 0) { asm volatile("s_waitcnt vmcnt(0)" ::: "memory"); }
            else        { asm volatile("s_waitcnt vmcnt(2)" ::: "memory"); }
            __builtin_amdgcn_s_barrier();
            if (t + 1 < 64) {
                int tn = t + 1;
                gld16(Kh + (size_t)(r0 + tn * 32) * 128 + inb, kn + L0);
                gld16(Kh + (size_t)(2048 + r0 + tn * 32) * 128 + inb, kn + L0 + 4096);
                size_t tail = (size_t)vh * 4096 + (size_t)(tn >> 1) * 128
                            + ((((tn & 1) << 2 | vs) ^ vdsw) << 4);
                gld16(Vh + (size_t)d0 * 8192 + tail, vn + L0);
                gld16(Vh + (size_t)(d0 + 32) * 8192 + tail, vn + L0 + 4096);
            }
            asm volatile("" ::: "memory");
#pragma unroll
            for (int jt = 0; jt < 2; ++jt) {
                const char* rp = kc + (khalf * 32 + jt * 16 + li) * 128;
                short8 kb0 = *(const short8*)(rp + ((g * 16) ^ sw));
                short8 kb1 = *(const short8*)(rp + ((64 + g * 16) ^ sw));
                f32x4 acc = {0.f, 0.f, 0.f, 0.f};
                acc = __builtin_amdgcn_mfma_f32_16x16x32_bf16(kb0, qa0, acc, 0, 0, 0);
                acc = __builtin_amdgcn_mfma_f32_16x16x32_bf16(kb1, qa1, acc, 0, 0, 0);
                f32x4 ev;
#pragma unroll
                for (int r = 0; r < 4; ++r) ev[r] = __expf(acc[r] * 0.125f) * iz;
                *(f32x4*)(WH + (size_t)(qr + li) * NN + khalf * 2048 + t * 32 + jt * 16 + g * 4) = ev;
                uint pk0 = (uint)f2bf(ev[0]) | ((uint)f2bf(ev[1]) << 16);
                uint pk1 = (uint)f2bf(ev[2]) | ((uint)f2bf(ev[3]) << 16);
                int boff = (li * 128 + jt * 32 + g * 8) ^ sw;
                *(uint2*)(myp + boff) = make_uint2(pk0, pk1);
            }
            {
                int rbp = (li * 128 + g * 16) ^ sw;
                short8 pa = *(const short8*)(myp + rbp);
#pragma unroll
                for (int dt = 0; dt < 4; ++dt) {
                    const char* vrp = vc + (dt * 16 + li) * 128 + vro;
                    short8 vbf = *(const short8*)(vrp);
                    pv[dt] = __builtin_amdgcn_mfma_f32_16x16x32_bf16(pa, vbf, pv[dt], 0, 0, 0);
                }
            }
            char* tmp = kc; kc = kn; kn = tmp;
            tmp = vc; vc = vn; vn = tmp;
        }
    }

    // ---- combine k-half pairs (attstage overlays pbuf) ----
    __syncthreads();
    if (khalf == 1) {
#pragma unroll
        for (int dt = 0; dt < 4; ++dt)
#pragma unroll
            for (int r = 0; r < 4; ++r)
                attstage[(rgrp * 16 + g * 4 + r) * 64 + dt * 16 + li] = pv[dt][r];
    }
    __syncthreads();
    if (khalf == 0) {
#pragma unroll
        for (int dt = 0; dt < 4; ++dt)
#pragma unroll
            for (int r = 0; r < 4; ++r) {
                float v = pv[dt][r] + attstage[(rgrp * 16 + g * 4 + r) * 64 + dt * 16 + li];
                att[(size_t)(qr + g * 4 + r) * HID + h * HD + dt * 16 + li] = v;
            }
    }
}

// ---------------- Kernel C: output = att @ Wo + bo ----------------
__global__ __launch_bounds__(256) void out_kernel(
    const float* __restrict__ att, const float* __restrict__ Wo,
    const float* __restrict__ bo, float* __restrict__ outp)
{
    const int row0 = blockIdx.x * 16;
    const int tid = threadIdx.x;
    const int tx = tid & 15, ty = tid >> 4;

    __shared__ float as_[64][20];
    __shared__ float ws2[64][68];

    float acc[4] = {0.f, 0.f, 0.f, 0.f};

    for (int kc = 0; kc < HID; kc += 64) {
        {
            int i = tid >> 4, k4 = tid & 15;
            float4 v = *(const float4*)(att + (size_t)(row0 + i) * HID + kc + k4 * 4);
            as_[k4 * 4 + 0][i] = v.x; as_[k4 * 4 + 1][i] = v.y;
            as_[k4 * 4 + 2][i] = v.z; as_[k4 * 4 + 3][i] = v.w;
        }
#pragma unroll
        for (int it = 0; it < 4; ++it) {
            int f = it * 256 + tid;
            int k = f >> 4, c4 = f & 15;
            float4 v = *(const float4*)(Wo + (size_t)(kc + k) * HD + c4 * 4);
            *(float4*)&ws2[k][c4 * 4] = v;
        }
        __syncthreads();
        for (int k = 0; k < 64; ++k) {
            float a = as_[k][ty];
            float4 b0 = *(const float4*)&ws2[k][tx * 4];
            acc[0] = fmaf(a, b0.x, acc[0]);
            acc[1] = fmaf(a, b0.y, acc[1]);
            acc[2] = fmaf(a, b0.z, acc[2]);
            acc[3] = fmaf(a, b0.w, acc[3]);
        }
        __syncthreads();
    }

    float4 v;
    v.x = acc[0] + bo[tx * 4 + 0];
    v.y = acc[1] + bo[tx * 4 + 1];
    v.z = acc[2] + bo[tx * 4 + 2];
    v.w = acc[3] + bo[tx * 4 + 3];
    *(float4*)(outp + (size_t)(row0 + ty) * HD + tx * 4) = v;
}

extern "C" void kernel_launch(void* const* d_in, const int* in_sizes, int n_in,
                              void* d_out, int out_size, void* d_ws, size_t ws_size,
                              hipStream_t stream) {
    const float* x  = (const float*)d_in[0];
    const float* Wq = (const float*)d_in[1];
    const float* bq = (const float*)d_in[2];
    const float* Wk = (const float*)d_in[3];
    const float* bk = (const float*)d_in[4];
    const float* Wv = (const float*)d_in[5];
    const float* bv = (const float*)d_in[6];
    const float* Wo = (const float*)d_in[7];
    const float* bo = (const float*)d_in[8];

    float* out  = (float*)d_out;
    float* wout = out + (size_t)NN * HD;

    char* wsb = (char*)d_ws;
    ushort* Qb  = (ushort*)wsb;                           // 4 MB
    char*   Kbs = wsb + 4u * 1024u * 1024u;               // 4 MB (swizzled)
    char*   Vts = wsb + 8u * 1024u * 1024u;               // 4 MB (swizzled)
    float*  att = (float*)(wsb + 12u * 1024u * 1024u);    // 8 MB
    ushort* xh  = (ushort*)(wsb + 20u * 1024u * 1024u);   // 4 MB
    ushort* xl  = (ushort*)(wsb + 24u * 1024u * 1024u);   // 4 MB
    ushort* Wph = (ushort*)(wsb + 28u * 1024u * 1024u);   // 1.5 MB
    ushort* Wpl = (ushort*)(wsb + 30u * 1024u * 1024u);   // 1.5 MB

    hipLaunchKernelGGL(cvt_x_kernel, dim3(1024), dim3(256), 0, stream, x, xh, xl);
    hipLaunchKernelGGL(cvt_w_kernel, dim3(2, 16, 3), dim3(256), 0, stream,
                       Wq, Wk, Wv, Wph, Wpl);
    hipLaunchKernelGGL(qkv_mfma_kernel, dim3(8, 32, 3), dim3(256), 0, stream,
                       xh, xl, Wph, Wpl, bq, bk, bv, Qb, Kbs, Vts);
    hipLaunchKernelGGL(attn_kernel, dim3(1024), dim3(256), 0, stream,
                       Qb, Kbs, Vts, wout, att);
    hipLaunchKernelGGL(out_kernel, dim3(256), dim3(256), 0, stream,
                       att, Wo, bo, out);
}

// Round 16
// 236.032 us; speedup vs baseline: 1.1037x; 1.1037x over previous
//
#include <hip/hip_runtime.h>

#define NN 4096
#define HID 512
#define NH 8
#define HD 64

typedef __attribute__((ext_vector_type(8))) short short8;
typedef __attribute__((ext_vector_type(4))) float f32x4;

__device__ __forceinline__ ushort f2bf(float f) {
    unsigned u = __float_as_uint(f);
    return (ushort)((u + 0x7FFFu + ((u >> 16) & 1u)) >> 16);   // RNE
}
__device__ __forceinline__ float bf2f(ushort h) {
    return __uint_as_float((unsigned)h << 16);
}

__device__ __forceinline__ void gld16(const void* g, void* l) {
    __builtin_amdgcn_global_load_lds(
        (const __attribute__((address_space(1))) void*)g,
        (__attribute__((address_space(3))) void*)l, 16, 0, 0);
}

// ---------------- cvt_x: x (f32) -> xh + xl (bf16 split) ----------------
__global__ __launch_bounds__(256) void cvt_x_kernel(
    const float* __restrict__ x, ushort* __restrict__ xh, ushort* __restrict__ xl)
{
    int i = (blockIdx.x * 256 + threadIdx.x) * 8;
    float4 v0 = *(const float4*)(x + i);
    float4 v1 = *(const float4*)(x + i + 4);
    float v[8] = {v0.x, v0.y, v0.z, v0.w, v1.x, v1.y, v1.z, v1.w};
    ushort h[8], l[8];
#pragma unroll
    for (int j = 0; j < 8; ++j) {
        h[j] = f2bf(v[j]);
        l[j] = f2bf(v[j] - bf2f(h[j]));
    }
    ushort4 u;
    u.x = h[0]; u.y = h[1]; u.z = h[2]; u.w = h[3]; *(ushort4*)(xh + i) = u;
    u.x = h[4]; u.y = h[5]; u.z = h[6]; u.w = h[7]; *(ushort4*)(xh + i + 4) = u;
    u.x = l[0]; u.y = l[1]; u.z = l[2]; u.w = l[3]; *(ushort4*)(xl + i) = u;
    u.x = l[4]; u.y = l[5]; u.z = l[6]; u.w = l[7]; *(ushort4*)(xl + i + 4) = u;
}

// ---------------- cvt_w: W (f32 [512][512]) -> packed hi/lo bf16 ----------------
__global__ __launch_bounds__(256) void cvt_w_kernel(
    const float* __restrict__ Wq, const float* __restrict__ Wk,
    const float* __restrict__ Wv,
    ushort* __restrict__ Wph, ushort* __restrict__ Wpl)
{
    const int mat = blockIdx.z;
    const float* W = (mat == 0) ? Wq : ((mat == 1) ? Wk : Wv);
    const int col = blockIdx.x * 256 + threadIdx.x;
    const int kcb = blockIdx.y;
    ushort* dh = Wph + (size_t)mat * 262144 + kcb * 16384 + col * 32;
    ushort* dl = Wpl + (size_t)mat * 262144 + kcb * 16384 + col * 32;
#pragma unroll
    for (int k4 = 0; k4 < 8; ++k4) {
        ushort4 uh, ul;
#pragma unroll
        for (int j = 0; j < 4; ++j) {
            float v = W[(size_t)(kcb * 32 + k4 * 4 + j) * HID + col];
            ushort h = f2bf(v);
            (&uh.x)[j] = h;
            (&ul.x)[j] = f2bf(v - bf2f(h));
        }
        *(ushort4*)(dh + k4 * 4) = uh;
        *(ushort4*)(dl + k4 * 4) = ul;
    }
}

// ---------------- qkv via MFMA, 3-split (xh@Wh + xh@Wl + xl@Wh) ----------------
__global__ __launch_bounds__(256) void qkv_mfma_kernel(
    const ushort* __restrict__ xh, const ushort* __restrict__ xl,
    const ushort* __restrict__ Wph, const ushort* __restrict__ Wpl,
    const float* __restrict__ bq, const float* __restrict__ bk,
    const float* __restrict__ bv,
    ushort* __restrict__ Qb, char* __restrict__ Kbs, char* __restrict__ Vts)
{
    const int mat = blockIdx.z;
    const int row0 = blockIdx.y * 128;
    const int col0 = blockIdx.x * 64;
    const int tid = threadIdx.x;
    const int w = tid >> 6, lane = tid & 63, g = lane >> 4, li = lane & 15;
    const ushort* Bh = Wph + (size_t)mat * 262144;
    const ushort* Bl = Wpl + (size_t)mat * 262144;
    const float* bias = (mat == 0) ? bq : ((mat == 1) ? bk : bv);

    __shared__ __align__(16) char smem[18432];

    f32x4 acc[2][4];
#pragma unroll
    for (int sb = 0; sb < 2; ++sb)
#pragma unroll
        for (int cf = 0; cf < 4; ++cf) acc[sb][cf] = (f32x4){0.f, 0.f, 0.f, 0.f};

    const ushort* xr0h = xh + (size_t)(row0 + w * 32 + li) * HID;
    const ushort* xr1h = xr0h + 16 * HID;
    const ushort* xr0l = xl + (size_t)(row0 + w * 32 + li) * HID;
    const ushort* xr1l = xr0l + 16 * HID;

#pragma unroll 2
    for (int kcb = 0; kcb < 16; ++kcb) {
        const int ko = kcb * 32 + g * 8;
        short8 a0h = *(const short8*)(xr0h + ko);
        short8 a1h = *(const short8*)(xr1h + ko);
        short8 a0l = *(const short8*)(xr0l + ko);
        short8 a1l = *(const short8*)(xr1l + ko);
        const ushort* bbh = Bh + kcb * 16384 + (col0 + li) * 32 + g * 8;
        const ushort* bbl = Bl + kcb * 16384 + (col0 + li) * 32 + g * 8;
#pragma unroll
        for (int cf = 0; cf < 4; ++cf) {
            short8 bhf = *(const short8*)(bbh + cf * 512);
            short8 blf = *(const short8*)(bbl + cf * 512);
            acc[0][cf] = __builtin_amdgcn_mfma_f32_16x16x32_bf16(a0l, bhf, acc[0][cf], 0, 0, 0);
            acc[0][cf] = __builtin_amdgcn_mfma_f32_16x16x32_bf16(a0h, blf, acc[0][cf], 0, 0, 0);
            acc[0][cf] = __builtin_amdgcn_mfma_f32_16x16x32_bf16(a0h, bhf, acc[0][cf], 0, 0, 0);
            acc[1][cf] = __builtin_amdgcn_mfma_f32_16x16x32_bf16(a1l, bhf, acc[1][cf], 0, 0, 0);
            acc[1][cf] = __builtin_amdgcn_mfma_f32_16x16x32_bf16(a1h, blf, acc[1][cf], 0, 0, 0);
            acc[1][cf] = __builtin_amdgcn_mfma_f32_16x16x32_bf16(a1h, bhf, acc[1][cf], 0, 0, 0);
        }
    }

    float bv_f[4];
#pragma unroll
    for (int cf = 0; cf < 4; ++cf) bv_f[cf] = bias[col0 + cf * 16 + li];

    const int head = col0 >> 6;
    if (mat < 2) {
        ushort* st = (ushort*)smem;          // [128][72]
#pragma unroll
        for (int sb = 0; sb < 2; ++sb)
#pragma unroll
            for (int cf = 0; cf < 4; ++cf)
#pragma unroll
                for (int r = 0; r < 4; ++r)
                    st[(w * 32 + sb * 16 + g * 4 + r) * 72 + cf * 16 + li] =
                        f2bf(acc[sb][cf][r] + bv_f[cf]);
        __syncthreads();
        int row = tid >> 1, hf = tid & 1;
        const ushort* src = st + row * 72 + hf * 32;
        if (mat == 0) {
            ushort* dst = Qb + ((size_t)head * NN + row0 + row) * HD + hf * 32;
#pragma unroll
            for (int c = 0; c < 4; ++c)
                *(uint4*)(dst + c * 8) = *(const uint4*)(src + c * 8);
        } else {
            char* dst = Kbs + ((size_t)head * NN + row0 + row) * 128;
#pragma unroll
            for (int j8 = 0; j8 < 4; ++j8) {
                int j = hf * 4 + j8;
                *(uint4*)(dst + ((j * 16) ^ ((row & 7) << 4))) =
                    *(const uint4*)(st + row * 72 + j * 8);
            }
        }
    } else {
        ushort* vst = (ushort*)smem;         // [64][136]
#pragma unroll
        for (int sb = 0; sb < 2; ++sb)
#pragma unroll
            for (int cf = 0; cf < 4; ++cf) {
                ushort4 pk;
                pk.x = f2bf(acc[sb][cf][0] + bv_f[cf]);
                pk.y = f2bf(acc[sb][cf][1] + bv_f[cf]);
                pk.z = f2bf(acc[sb][cf][2] + bv_f[cf]);
                pk.w = f2bf(acc[sb][cf][3] + bv_f[cf]);
                *(ushort4*)(vst + (cf * 16 + li) * 136 + w * 32 + sb * 16 + g * 4) = pk;
            }
        __syncthreads();
        int cl = tid >> 2, q = tid & 3;
        int dsw = (cl & 7) << 4;
        char* dstrow = Vts + (size_t)(col0 + cl) * (NN * 2);
        int colb0 = (row0 + q * 32) * 2;
#pragma unroll
        for (int k8 = 0; k8 < 4; ++k8)
            *(uint4*)(dstrow + ((colb0 + k8 * 16) ^ dsw)) =
                *(const uint4*)(vst + cl * 136 + q * 32 + k8 * 8);
    }
}

// ---------------- Kernel B: fused attention ----------------
// grid 1024, block 256 (4 waves). 32 q-rows/block; wave w: rgrp=w>>1 (16 rows),
// khalf=w&1 (2048 k). 32-col k-tiles, 64 iters/pass. LDS 40KB -> 4 blocks/CU
// (160KB exact). Counted-vmcnt pipeline. h = bid&7 (XCD-pinned).
__global__ __launch_bounds__(256, 4) void attn_kernel(
    const ushort* __restrict__ Qb, const char* __restrict__ Kbs,
    const char* __restrict__ Vts,
    float* __restrict__ wout, float* __restrict__ att)
{
    const int bid = blockIdx.x;
    const int h = bid & 7;
    const int row0 = (bid >> 3) * 32;
    const int tid = threadIdx.x;
    const int w = tid >> 6, lane = tid & 63;
    const int g = lane >> 4, li = lane & 15;
    const int rgrp = w >> 1, khalf = w & 1;
    const int qr = row0 + rgrp * 16;

    const ushort* Qh = Qb + (size_t)h * NN * HD;
    const char* Kh = Kbs + (size_t)h * NN * 128;
    const char* Vh = Vts + (size_t)h * HD * NN * 2;
    float* WH = wout + ((size_t)h << 24);

    // LDS 40960B: kbuf0|kbuf1 8KB, vbuf0|vbuf1 8KB, pbuf 8KB (4x2KB).
    __shared__ __align__(16) char smem[40960];
    char* kbuf0 = smem;
    char* kbuf1 = smem + 8192;
    char* vbuf0 = smem + 16384;
    char* vbuf1 = smem + 24576;
    char* pbuf  = smem + 32768;
    float* zpart = (float*)(smem + 32768);      // [4][16] overlay
    float* attstage = (float*)(smem + 32768);   // [32][64] overlay

    const short8 qa0 = *(const short8*)(Qh + (size_t)(qr + li) * HD + g * 8);
    const short8 qa1 = *(const short8*)(Qh + (size_t)(qr + li) * HD + 32 + g * 8);
    const int sw = (li & 7) << 4;

    // ---- staging geometry (per thread, 2 gld16 per 8KB buffer) ----
    const int r0 = w * 8 + (lane >> 3);
    const int inb = (lane & 7) * 16;
    const int L0 = w * 1024 + lane * 16;
    // V slot map (verified R14)
    const int d0 = r0;
    const int hs = (lane & 7) ^ (d0 & 7);
    const int vh = hs >> 2, vs = hs & 3;
    const int vdsw = d0 & 7;
    const int vro = (((khalf << 2) | g) ^ (li & 7)) << 4;

    // ---- Pass A: Z (triple-buffered K: kbuf0, kbuf1, vbuf0) ----
    float zsum = 0.f;
    {
        char* c0 = kbuf0; char* c1 = kbuf1; char* c2 = vbuf0;
        gld16(Kh + (size_t)(r0) * 128 + inb, c0 + L0);
        gld16(Kh + (size_t)(2048 + r0) * 128 + inb, c0 + L0 + 4096);
        gld16(Kh + (size_t)(r0 + 32) * 128 + inb, c1 + L0);
        gld16(Kh + (size_t)(2048 + r0 + 32) * 128 + inb, c1 + L0 + 4096);
        asm volatile("" ::: "memory");
        for (int t = 0; t < 64; ++t) {
            if (t < 63) { asm volatile("s_waitcnt vmcnt(2)" ::: "memory"); }
            else        { asm volatile("s_waitcnt vmcnt(0)" ::: "memory"); }
            __builtin_amdgcn_s_barrier();
            if (t + 2 < 64) {
                gld16(Kh + (size_t)(r0 + (t + 2) * 32) * 128 + inb, c2 + L0);
                gld16(Kh + (size_t)(2048 + r0 + (t + 2) * 32) * 128 + inb, c2 + L0 + 4096);
            }
            asm volatile("" ::: "memory");
#pragma unroll
            for (int jt = 0; jt < 2; ++jt) {
                const char* rp = c0 + (khalf * 32 + jt * 16 + li) * 128;
                short8 kb0 = *(const short8*)(rp + ((g * 16) ^ sw));
                short8 kb1 = *(const short8*)(rp + ((64 + g * 16) ^ sw));
                f32x4 acc = {0.f, 0.f, 0.f, 0.f};
                acc = __builtin_amdgcn_mfma_f32_16x16x32_bf16(kb0, qa0, acc, 0, 0, 0);
                acc = __builtin_amdgcn_mfma_f32_16x16x32_bf16(kb1, qa1, acc, 0, 0, 0);
#pragma unroll
                for (int r = 0; r < 4; ++r) zsum += __expf(acc[r] * 0.125f);
            }
            char* tmp = c0; c0 = c1; c1 = c2; c2 = tmp;
        }
    }
    zsum += __shfl_xor(zsum, 16);
    zsum += __shfl_xor(zsum, 32);
    if (lane < 16) zpart[w * 16 + li] = zsum;
    __syncthreads();
    const float iz = 1.0f / (zpart[(rgrp * 2) * 16 + li] + zpart[(rgrp * 2 + 1) * 16 + li]);
    __syncthreads();   // zpart consumed before pbuf overlay is written

    // ---- Pass B: normalized weights + P@V ----
    f32x4 pv[4];
#pragma unroll
    for (int dt = 0; dt < 4; ++dt) pv[dt] = (f32x4){0.f, 0.f, 0.f, 0.f};
    char* myp = pbuf + w * 2048;

    {
        char* kc = kbuf0; char* kn = kbuf1;
        char* vc = vbuf0; char* vn = vbuf1;
        // prologue t=0
        gld16(Kh + (size_t)(r0) * 128 + inb, kc + L0);
        gld16(Kh + (size_t)(2048 + r0) * 128 + inb, kc + L0 + 4096);
        {
            size_t tail0 = (size_t)vh * 4096 + ((vs ^ vdsw) << 4);
            gld16(Vh + (size_t)d0 * 8192 + tail0, vc + L0);
            gld16(Vh + (size_t)(d0 + 32) * 8192 + tail0, vc + L0 + 4096);
        }
        asm volatile("" ::: "memory");
        for (int t = 0; t < 64; ++t) {
            if (t == 0) { asm volatile("s_waitcnt vmcnt(0)" ::: "memory"); }
            else        { asm volatile("s_waitcnt vmcnt(2)" ::: "memory"); }
            __builtin_amdgcn_s_barrier();
            if (t + 1 < 64) {
                int tn = t + 1;
                gld16(Kh + (size_t)(r0 + tn * 32) * 128 + inb, kn + L0);
                gld16(Kh + (size_t)(2048 + r0 + tn * 32) * 128 + inb, kn + L0 + 4096);
                size_t tail = (size_t)vh * 4096 + (size_t)(tn >> 1) * 128
                            + ((((tn & 1) << 2 | vs) ^ vdsw) << 4);
                gld16(Vh + (size_t)d0 * 8192 + tail, vn + L0);
                gld16(Vh + (size_t)(d0 + 32) * 8192 + tail, vn + L0 + 4096);
            }
            asm volatile("" ::: "memory");
#pragma unroll
            for (int jt = 0; jt < 2; ++jt) {
                const char* rp = kc + (khalf * 32 + jt * 16 + li) * 128;
                short8 kb0 = *(const short8*)(rp + ((g * 16) ^ sw));
                short8 kb1 = *(const short8*)(rp + ((64 + g * 16) ^ sw));
                f32x4 acc = {0.f, 0.f, 0.f, 0.f};
                acc = __builtin_amdgcn_mfma_f32_16x16x32_bf16(kb0, qa0, acc, 0, 0, 0);
                acc = __builtin_amdgcn_mfma_f32_16x16x32_bf16(kb1, qa1, acc, 0, 0, 0);
                f32x4 ev;
#pragma unroll
                for (int r = 0; r < 4; ++r) ev[r] = __expf(acc[r] * 0.125f) * iz;
                *(f32x4*)(WH + (size_t)(qr + li) * NN + khalf * 2048 + t * 32 + jt * 16 + g * 4) = ev;
                uint pk0 = (uint)f2bf(ev[0]) | ((uint)f2bf(ev[1]) << 16);
                uint pk1 = (uint)f2bf(ev[2]) | ((uint)f2bf(ev[3]) << 16);
                int boff = (li * 128 + jt * 32 + g * 8) ^ sw;
                *(uint2*)(myp + boff) = make_uint2(pk0, pk1);
            }
            // PV for this tile (32 k): P row li, V rows dt*16+li
            {
                int rbp = (li * 128 + g * 16) ^ sw;
                short8 pa = *(const short8*)(myp + rbp);
#pragma unroll
                for (int dt = 0; dt < 4; ++dt) {
                    const char* vrp = vc + (dt * 16 + li) * 128 + vro;
                    short8 vbf = *(const short8*)(vrp);
                    pv[dt] = __builtin_amdgcn_mfma_f32_16x16x32_bf16(pa, vbf, pv[dt], 0, 0, 0);
                }
            }
            char* tmp = kc; kc = kn; kn = tmp;
            tmp = vc; vc = vn; vn = tmp;
        }
    }

    // ---- combine k-half pairs (attstage overlays pbuf) ----
    __syncthreads();
    if (khalf == 1) {
#pragma unroll
        for (int dt = 0; dt < 4; ++dt)
#pragma unroll
            for (int r = 0; r < 4; ++r)
                attstage[(rgrp * 16 + g * 4 + r) * 64 + dt * 16 + li] = pv[dt][r];
    }
    __syncthreads();
    if (khalf == 0) {
#pragma unroll
        for (int dt = 0; dt < 4; ++dt)
#pragma unroll
            for (int r = 0; r < 4; ++r) {
                float v = pv[dt][r] + attstage[(rgrp * 16 + g * 4 + r) * 64 + dt * 16 + li];
                att[(size_t)(qr + g * 4 + r) * HID + h * HD + dt * 16 + li] = v;
            }
    }
}

// ---------------- Kernel C: output = att @ Wo + bo ----------------
__global__ __launch_bounds__(256) void out_kernel(
    const float* __restrict__ att, const float* __restrict__ Wo,
    const float* __restrict__ bo, float* __restrict__ outp)
{
    const int row0 = blockIdx.x * 16;
    const int tid = threadIdx.x;
    const int tx = tid & 15, ty = tid >> 4;

    __shared__ float as_[64][20];
    __shared__ float ws2[64][68];

    float acc[4] = {0.f, 0.f, 0.f, 0.f};

    for (int kc = 0; kc < HID; kc += 64) {
        {
            int i = tid >> 4, k4 = tid & 15;
            float4 v = *(const float4*)(att + (size_t)(row0 + i) * HID + kc + k4 * 4);
            as_[k4 * 4 + 0][i] = v.x; as_[k4 * 4 + 1][i] = v.y;
            as_[k4 * 4 + 2][i] = v.z; as_[k4 * 4 + 3][i] = v.w;
        }
#pragma unroll
        for (int it = 0; it < 4; ++it) {
            int f = it * 256 + tid;
            int k = f >> 4, c4 = f & 15;
            float4 v = *(const float4*)(Wo + (size_t)(kc + k) * HD + c4 * 4);
            *(float4*)&ws2[k][c4 * 4] = v;
        }
        __syncthreads();
        for (int k = 0; k < 64; ++k) {
            float a = as_[k][ty];
            float4 b0 = *(const float4*)&ws2[k][tx * 4];
            acc[0] = fmaf(a, b0.x, acc[0]);
            acc[1] = fmaf(a, b0.y, acc[1]);
            acc[2] = fmaf(a, b0.z, acc[2]);
            acc[3] = fmaf(a, b0.w, acc[3]);
        }
        __syncthreads();
    }

    float4 v;
    v.x = acc[0] + bo[tx * 4 + 0];
    v.y = acc[1] + bo[tx * 4 + 1];
    v.z = acc[2] + bo[tx * 4 + 2];
    v.w = acc[3] + bo[tx * 4 + 3];
    *(float4*)(outp + (size_t)(row0 + ty) * HD + tx * 4) = v;
}

extern "C" void kernel_launch(void* const* d_in, const int* in_sizes, int n_in,
                              void* d_out, int out_size, void* d_ws, size_t ws_size,
                              hipStream_t stream) {
    const float* x  = (const float*)d_in[0];
    const float* Wq = (const float*)d_in[1];
    const float* bq = (const float*)d_in[2];
    const float* Wk = (const float*)d_in[3];
    const float* bk = (const float*)d_in[4];
    const float* Wv = (const float*)d_in[5];
    const float* bv = (const float*)d_in[6];
    const float* Wo = (const float*)d_in[7];
    const float* bo = (const float*)d_in[8];

    float* out  = (float*)d_out;
    float* wout = out + (size_t)NN * HD;

    char* wsb = (char*)d_ws;
    ushort* Qb  = (ushort*)wsb;                           // 4 MB
    char*   Kbs = wsb + 4u * 1024u * 1024u;               // 4 MB (swizzled)
    char*   Vts = wsb + 8u * 1024u * 1024u;               // 4 MB (swizzled)
    float*  att = (float*)(wsb + 12u * 1024u * 1024u);    // 8 MB
    ushort* xh  = (ushort*)(wsb + 20u * 1024u * 1024u);   // 4 MB
    ushort* xl  = (ushort*)(wsb + 24u * 1024u * 1024u);   // 4 MB
    ushort* Wph = (ushort*)(wsb + 28u * 1024u * 1024u);   // 1.5 MB
    ushort* Wpl = (ushort*)(wsb + 30u * 1024u * 1024u);   // 1.5 MB

    hipLaunchKernelGGL(cvt_x_kernel, dim3(1024), dim3(256), 0, stream, x, xh, xl);
    hipLaunchKernelGGL(cvt_w_kernel, dim3(2, 16, 3), dim3(256), 0, stream,
                       Wq, Wk, Wv, Wph, Wpl);
    hipLaunchKernelGGL(qkv_mfma_kernel, dim3(8, 32, 3), dim3(256), 0, stream,
                       xh, xl, Wph, Wpl, bq, bk, bv, Qb, Kbs, Vts);
    hipLaunchKernelGGL(attn_kernel, dim3(1024), dim3(256), 0, stream,
                       Qb, Kbs, Vts, wout, att);
    hipLaunchKernelGGL(out_kernel, dim3(256), dim3(256), 0, stream,
                       att, Wo, bo, out);
}